// Round 9
// baseline (6731.474 us; speedup 1.0000x reference)
//
#include <hip/hip_runtime.h>

#define M_DIM 8192
#define K_DIM 4096
#define N_DIM 11008
#define BM 256
#define BN 256
#define BK 32
#define TILES_M (M_DIM / BM)     // 32
#define TILES_N (N_DIM / BN)     // 43
#define NT (K_DIM / BK)          // 128
#define NWG (TILES_M * TILES_N)  // 1376 = 8 * 172

typedef __attribute__((ext_vector_type(8))) short bf16x8;
typedef __attribute__((ext_vector_type(4))) float f32x4;
typedef __attribute__((ext_vector_type(8))) unsigned short u16x8;

__device__ __forceinline__ unsigned short f2bf_rne(float f) {
    unsigned int u = __float_as_uint(f);
    unsigned int r = (u + 0x7FFFu + ((u >> 16) & 1u)) >> 16;
    return (unsigned short)r;
}

__device__ __forceinline__ void gload_lds16(const void* g, void* l) {
    __builtin_amdgcn_global_load_lds(
        (const __attribute__((address_space(1))) void*)g,
        (__attribute__((address_space(3))) void*)l, 16, 0, 0);
}

// ---------------- x: fp32 -> bf16 (8 elems / thread) ----------------
__global__ __launch_bounds__(256) void cast_x_kernel(const float* __restrict__ x,
                                                     unsigned short* __restrict__ xb) {
    size_t t = (size_t)blockIdx.x * 256 + threadIdx.x;
    const float4* p = reinterpret_cast<const float4*>(x) + 2 * t;
    float4 a = p[0];
    float4 b = p[1];
    u16x8 o;
    o[0] = f2bf_rne(a.x); o[1] = f2bf_rne(a.y); o[2] = f2bf_rne(a.z); o[3] = f2bf_rne(a.w);
    o[4] = f2bf_rne(b.x); o[5] = f2bf_rne(b.y); o[6] = f2bf_rne(b.z); o[7] = f2bf_rne(b.w);
    *reinterpret_cast<u16x8*>(xb + 8 * t) = o;
}

// ------- weight: per-128-group absmax scale, sign*scale -> bf16 -------
__global__ __launch_bounds__(256) void binarize_w_kernel(const float* __restrict__ w,
                                                         unsigned short* __restrict__ weff) {
    size_t t = (size_t)blockIdx.x * 256 + threadIdx.x;
    size_t group = t >> 5;
    int l32 = (int)(t & 31);
    const float4* src = reinterpret_cast<const float4*>(w + group * 128) + l32;
    float4 v = *src;
    float amax = fmaxf(fmaxf(fabsf(v.x), fabsf(v.y)), fmaxf(fabsf(v.z), fabsf(v.w)));
#pragma unroll
    for (int off = 16; off >= 1; off >>= 1)
        amax = fmaxf(amax, __shfl_xor(amax, off));
    float scale = fmaxf(amax, 1e-8f);
    unsigned short pb = f2bf_rne(scale);
    unsigned short nb = (unsigned short)(pb | 0x8000u);
    ushort4 o;
    o.x = (v.x == 0.0f) ? (unsigned short)0 : ((v.x > 0.0f) ? pb : nb);
    o.y = (v.y == 0.0f) ? (unsigned short)0 : ((v.y > 0.0f) ? pb : nb);
    o.z = (v.z == 0.0f) ? (unsigned short)0 : ((v.z > 0.0f) ? pb : nb);
    o.w = (v.w == 0.0f) ? (unsigned short)0 : ((v.w > 0.0f) ? pb : nb);
    *reinterpret_cast<ushort4*>(weff + group * 128 + (size_t)l32 * 4) = o;
}

// ---------------- GEMM: C[M][N] = Xb[M][K] * Weff[N][K]^T ----------------
// 256x256 tile, BK=32, 8 waves (2Mx4N), 64 KiB LDS double-buffer ->
// TWO blocks per CU. Inter-block overlap (m114) covers each block's
// read/drain troughs. Per K-step: stage(nxt) -> 12 frag reads -> 32 MFMA
// -> vmcnt(0) -> one barrier. 16x16x32 MFMA (conflict-free swizzle family).
__global__ __launch_bounds__(512, 4) void gemm_bin_kernel(
        const unsigned short* __restrict__ A,   // Xb  [M][K] bf16
        const unsigned short* __restrict__ B,   // Weff[N][K] bf16
        float* __restrict__ C) {
    __shared__ unsigned short lds[2][2][8192];  // [buf][A/B][256 rows * 32]

    const int bid = blockIdx.x;
    const int swz = (bid & 7) * (NWG / 8) + (bid >> 3);   // bijective: NWG % 8 == 0
    const int tm = swz / TILES_N;
    const int tn = swz % TILES_N;

    const int tid = threadIdx.x;
    const int wave = tid >> 6;
    const int lane = tid & 63;
    const int wm = wave >> 2;      // 0..1 -> A half (128 rows)
    const int wn = wave & 3;       // 0..3 -> B 64-row strip
    const int l15 = lane & 15;
    const int l4  = lane >> 4;

    // ---- staging: linear LDS dest, pre-swizzled global source ----
    // thread t covers 16B: row = t>>2 (0..127, +128 for chunk 2), slot = t&3.
    // source slot pre-XORed so LDS holds [row][slot ^ (row&3)] content.
    const int srow  = tid >> 2;                  // 0..127
    const int gslot = (tid & 3) ^ (srow & 3);    // (srow+128)&3 == srow&3
    const unsigned short* Asrc = A + (size_t)(tm * BM + srow) * K_DIM + gslot * 8;
    const unsigned short* Bsrc = B + (size_t)(tn * BN + srow) * K_DIM + gslot * 8;

    auto stage = [&](int buf, int kt) {
        gload_lds16(Asrc + kt, &lds[buf][0][tid * 8]);
        gload_lds16(Asrc + (size_t)128 * K_DIM + kt, &lds[buf][0][4096 + tid * 8]);
        gload_lds16(Bsrc + kt, &lds[buf][1][tid * 8]);
        gload_lds16(Bsrc + (size_t)128 * K_DIM + kt, &lds[buf][1][4096 + tid * 8]);
    };
    // frag read: row-major [256][32] + (slot ^= row&3) on 16B slots.
    // 8-lane LDS groups hit distinct-or-2-way banks (2-way is free, m136).
    auto readfrag = [&](const unsigned short* base, int rowl) -> bf16x8 {
        return *reinterpret_cast<const bf16x8*>(
            &base[rowl * 32 + ((l4 ^ (rowl & 3)) * 8)]);
    };

    f32x4 acc[8][4] = {};
    bf16x8 af[8], bf[4];

#define KSTEP(T, CUR, NXT)                                                      \
    {                                                                           \
        if ((T) + 1 < NT) stage(NXT, ((T) + 1) * BK);                           \
        _Pragma("unroll") for (int i_ = 0; i_ < 8; ++i_)                        \
            af[i_] = readfrag(&lds[CUR][0][0], wm * 128 + i_ * 16 + l15);       \
        _Pragma("unroll") for (int j_ = 0; j_ < 4; ++j_)                        \
            bf[j_] = readfrag(&lds[CUR][1][0], wn * 64 + j_ * 16 + l15);        \
        __builtin_amdgcn_s_setprio(1);                                          \
        _Pragma("unroll") for (int i_ = 0; i_ < 8; ++i_) {                      \
            _Pragma("unroll") for (int j_ = 0; j_ < 4; ++j_) {                  \
                acc[i_][j_] = __builtin_amdgcn_mfma_f32_16x16x32_bf16(          \
                    af[i_], bf[j_], acc[i_][j_], 0, 0, 0);                      \
            }                                                                   \
        }                                                                       \
        __builtin_amdgcn_s_setprio(0);                                          \
        if ((T) + 1 < NT) {                                                     \
            asm volatile("s_waitcnt vmcnt(0)" ::: "memory");                    \
            __builtin_amdgcn_s_barrier();                                       \
        }                                                                       \
    }

    // ---- prologue ----
    stage(0, 0);
    asm volatile("s_waitcnt vmcnt(0)" ::: "memory");
    __builtin_amdgcn_s_barrier();

#pragma unroll 1
    for (int t = 0; t < NT; t += 2) {
        KSTEP(t,     0, 1);
        KSTEP(t + 1, 1, 0);
    }

    // ---- epilogue: C/D layout col=lane&15, row=(lane>>4)*4+reg; NT stores ----
    const size_t crow0 = (size_t)tm * BM + wm * 128 + l4 * 4;
    const int ccol0 = tn * BN + wn * 64 + l15;
#pragma unroll
    for (int i = 0; i < 8; ++i) {
#pragma unroll
        for (int j = 0; j < 4; ++j) {
            float* cp = C + (crow0 + i * 16) * N_DIM + ccol0 + j * 16;
#pragma unroll
            for (int r = 0; r < 4; ++r)
                __builtin_nontemporal_store(acc[i][j][r], cp + (size_t)r * N_DIM);
        }
    }
}

extern "C" void kernel_launch(void* const* d_in, const int* in_sizes, int n_in,
                              void* d_out, int out_size, void* d_ws, size_t ws_size,
                              hipStream_t stream) {
    const float* x = (const float*)d_in[0];       // [4,2048,4096] fp32
    const float* w = (const float*)d_in[1];       // [11008,4096] fp32
    float* out = (float*)d_out;                   // [4,2048,11008] fp32

    unsigned short* xb = (unsigned short*)d_ws;                                        // 64 MiB
    unsigned short* weff = (unsigned short*)((char*)d_ws + (size_t)M_DIM * K_DIM * 2); // 86 MiB

    cast_x_kernel<<<(M_DIM * K_DIM / 8) / 256, 256, 0, stream>>>(x, xb);
    binarize_w_kernel<<<(N_DIM * K_DIM / 4) / 256, 256, 0, stream>>>(w, weff);
    gemm_bin_kernel<<<NWG, 512, 0, stream>>>(xb, weff, out);
}

// Round 10
// 997.715 us; speedup vs baseline: 6.7469x; 6.7469x over previous
//
#include <hip/hip_runtime.h>

#define M_DIM 8192
#define K_DIM 4096
#define N_DIM 11008
#define BM 128
#define BN 256
#define BK 32
#define TILES_M (M_DIM / BM)     // 64
#define TILES_N (N_DIM / BN)     // 43
#define NT (K_DIM / BK)          // 128
#define NWG (TILES_M * TILES_N)  // 2752 = 8 * 344

typedef __attribute__((ext_vector_type(8))) short bf16x8;
typedef __attribute__((ext_vector_type(4))) float f32x4;
typedef __attribute__((ext_vector_type(8))) unsigned short u16x8;

__device__ __forceinline__ unsigned short f2bf_rne(float f) {
    unsigned int u = __float_as_uint(f);
    unsigned int r = (u + 0x7FFFu + ((u >> 16) & 1u)) >> 16;
    return (unsigned short)r;
}

__device__ __forceinline__ void gload_lds16(const void* g, void* l) {
    __builtin_amdgcn_global_load_lds(
        (const __attribute__((address_space(1))) void*)g,
        (__attribute__((address_space(3))) void*)l, 16, 0, 0);
}

// ---------------- x: fp32 -> bf16 (8 elems / thread) ----------------
__global__ __launch_bounds__(256) void cast_x_kernel(const float* __restrict__ x,
                                                     unsigned short* __restrict__ xb) {
    size_t t = (size_t)blockIdx.x * 256 + threadIdx.x;
    const float4* p = reinterpret_cast<const float4*>(x) + 2 * t;
    float4 a = p[0];
    float4 b = p[1];
    u16x8 o;
    o[0] = f2bf_rne(a.x); o[1] = f2bf_rne(a.y); o[2] = f2bf_rne(a.z); o[3] = f2bf_rne(a.w);
    o[4] = f2bf_rne(b.x); o[5] = f2bf_rne(b.y); o[6] = f2bf_rne(b.z); o[7] = f2bf_rne(b.w);
    *reinterpret_cast<u16x8*>(xb + 8 * t) = o;
}

// ------- weight: per-128-group absmax scale, sign*scale -> bf16 -------
__global__ __launch_bounds__(256) void binarize_w_kernel(const float* __restrict__ w,
                                                         unsigned short* __restrict__ weff) {
    size_t t = (size_t)blockIdx.x * 256 + threadIdx.x;
    size_t group = t >> 5;
    int l32 = (int)(t & 31);
    const float4* src = reinterpret_cast<const float4*>(w + group * 128) + l32;
    float4 v = *src;
    float amax = fmaxf(fmaxf(fabsf(v.x), fabsf(v.y)), fmaxf(fabsf(v.z), fabsf(v.w)));
#pragma unroll
    for (int off = 16; off >= 1; off >>= 1)
        amax = fmaxf(amax, __shfl_xor(amax, off));
    float scale = fmaxf(amax, 1e-8f);
    unsigned short pb = f2bf_rne(scale);
    unsigned short nb = (unsigned short)(pb | 0x8000u);
    ushort4 o;
    o.x = (v.x == 0.0f) ? (unsigned short)0 : ((v.x > 0.0f) ? pb : nb);
    o.y = (v.y == 0.0f) ? (unsigned short)0 : ((v.y > 0.0f) ? pb : nb);
    o.z = (v.z == 0.0f) ? (unsigned short)0 : ((v.z > 0.0f) ? pb : nb);
    o.w = (v.w == 0.0f) ? (unsigned short)0 : ((v.w > 0.0f) ? pb : nb);
    *reinterpret_cast<ushort4*>(weff + group * 128 + (size_t)l32 * 4) = o;
}

// ---------------- GEMM: C[M][N] = Xb[M][K] * Weff[N][K]^T ----------------
// 128x256 tile, BK=32, 4 waves (2Mx2N, wave tile 64x128), 48 KiB LDS dbuf,
// __launch_bounds__(256,2) -> TWO blocks/CU at 2 waves/SIMD (256-reg cap,
// acc 128 + ~100 arch regs fit). Inter-block overlap (m114) covers each
// block's vmcnt/barrier trough. Swizzle for 64B rows: slot ^= (row>>1)&3
// (2-way max aliasing = free). One barrier per K-step.
__global__ __launch_bounds__(256, 2) void gemm_bin_kernel(
        const unsigned short* __restrict__ A,   // Xb  [M][K] bf16
        const unsigned short* __restrict__ B,   // Weff[N][K] bf16
        float* __restrict__ C) {
    __shared__ unsigned short lds[2][12288];  // [buf][ A 128x32 | B 256x32 ]

    const int bid = blockIdx.x;
    const int swz = (bid & 7) * (NWG / 8) + (bid >> 3);   // bijective: NWG % 8 == 0
    const int tm = swz / TILES_N;
    const int tn = swz % TILES_N;

    const int tid = threadIdx.x;
    const int wave = tid >> 6;
    const int lane = tid & 63;
    const int wm = wave >> 1;      // 0..1 -> M half (64 rows)
    const int wn = wave & 1;       // 0..1 -> N half (128 cols)
    const int l15 = lane & 15;
    const int l4  = lane >> 4;

    // ---- staging: linear LDS dest, pre-swizzled global source ----
    // thread t covers 16B: row = t>>2, slot = t&3; source col pre-XORed by
    // (row>>1)&3 (chunk-invariant: chunks add multiples of 64 rows).
    const int srow  = tid >> 2;                  // 0..63
    const int gslot = (tid & 3) ^ ((srow >> 1) & 3);
    const unsigned short* Asrc = A + (size_t)(tm * BM + srow) * K_DIM + gslot * 8;
    const unsigned short* Bsrc = B + (size_t)(tn * BN + srow) * K_DIM + gslot * 8;

    auto stage = [&](int buf, int kt) {
        gload_lds16(Asrc + kt,                      &lds[buf][tid * 8]);
        gload_lds16(Asrc + (size_t)64 * K_DIM + kt, &lds[buf][2048 + tid * 8]);
#pragma unroll
        for (int c = 0; c < 4; ++c)
            gload_lds16(Bsrc + (size_t)(c * 64) * K_DIM + kt,
                        &lds[buf][4096 + c * 2048 + tid * 8]);
    };
    // frag read: [row][32] rows of 64B; slot = l4 ^ ((row>>1)&3) -> banks
    // unique over 8-row periods, exactly 2 lanes/bank-span (free, m136).
    auto readA = [&](int buf, int mi) -> bf16x8 {
        int row = wm * 64 + mi * 16 + l15;
        return *reinterpret_cast<const bf16x8*>(
            &lds[buf][row * 32 + ((l4 ^ ((row >> 1) & 3)) * 8)]);
    };
    auto readB = [&](int buf, int nj) -> bf16x8 {
        int row = wn * 128 + nj * 16 + l15;
        return *reinterpret_cast<const bf16x8*>(
            &lds[buf][4096 + row * 32 + ((l4 ^ ((row >> 1) & 3)) * 8)]);
    };

    f32x4 acc[4][8] = {};
    bf16x8 af[4], bf[8];

#define KSTEP(T, CUR, NXT)                                                      \
    {                                                                           \
        if ((T) + 1 < NT) stage(NXT, ((T) + 1) * BK);                           \
        _Pragma("unroll") for (int mi_ = 0; mi_ < 4; ++mi_)                     \
            af[mi_] = readA(CUR, mi_);                                          \
        _Pragma("unroll") for (int nj_ = 0; nj_ < 8; ++nj_)                     \
            bf[nj_] = readB(CUR, nj_);                                          \
        __builtin_amdgcn_s_setprio(1);                                          \
        _Pragma("unroll") for (int mi_ = 0; mi_ < 4; ++mi_) {                   \
            _Pragma("unroll") for (int nj_ = 0; nj_ < 8; ++nj_) {               \
                acc[mi_][nj_] = __builtin_amdgcn_mfma_f32_16x16x32_bf16(        \
                    af[mi_], bf[nj_], acc[mi_][nj_], 0, 0, 0);                  \
            }                                                                   \
        }                                                                       \
        __builtin_amdgcn_s_setprio(0);                                          \
        if ((T) + 1 < NT) {                                                     \
            asm volatile("s_waitcnt vmcnt(0)" ::: "memory");                    \
            __builtin_amdgcn_s_barrier();                                       \
        }                                                                       \
    }

    // ---- prologue ----
    stage(0, 0);
    asm volatile("s_waitcnt vmcnt(0)" ::: "memory");
    __builtin_amdgcn_s_barrier();

#pragma unroll 1
    for (int t = 0; t < NT; t += 2) {
        KSTEP(t,     0, 1);
        KSTEP(t + 1, 1, 0);
    }

    // ---- epilogue: C/D layout col=lane&15, row=(lane>>4)*4+reg; NT stores ----
    const size_t crow0 = (size_t)tm * BM + wm * 64 + l4 * 4;
    const int ccol0 = tn * BN + wn * 128 + l15;
#pragma unroll
    for (int mi = 0; mi < 4; ++mi) {
#pragma unroll
        for (int nj = 0; nj < 8; ++nj) {
            float* cp = C + (crow0 + mi * 16) * N_DIM + ccol0 + nj * 16;
#pragma unroll
            for (int r = 0; r < 4; ++r)
                __builtin_nontemporal_store(acc[mi][nj][r], cp + (size_t)r * N_DIM);
        }
    }
}

extern "C" void kernel_launch(void* const* d_in, const int* in_sizes, int n_in,
                              void* d_out, int out_size, void* d_ws, size_t ws_size,
                              hipStream_t stream) {
    const float* x = (const float*)d_in[0];       // [4,2048,4096] fp32
    const float* w = (const float*)d_in[1];       // [11008,4096] fp32
    float* out = (float*)d_out;                   // [4,2048,11008] fp32

    unsigned short* xb = (unsigned short*)d_ws;                                        // 64 MiB
    unsigned short* weff = (unsigned short*)((char*)d_ws + (size_t)M_DIM * K_DIM * 2); // 86 MiB

    cast_x_kernel<<<(M_DIM * K_DIM / 8) / 256, 256, 0, stream>>>(x, xb);
    binarize_w_kernel<<<(N_DIM * K_DIM / 4) / 256, 256, 0, stream>>>(w, weff);
    gemm_bin_kernel<<<NWG, 256, 0, stream>>>(xb, weff, out);
}